// Round 2
// baseline (752.955 us; speedup 1.0000x reference)
//
#include <hip/hip_runtime.h>

typedef float f32x4 __attribute__((ext_vector_type(4)));

// Vector path (requires N % 4 == 0): one thread owns 4 consecutive windows.
// Layout of samples: [(pixel p)*N + n]*3 + c, p = i*12 + j. A 4-window group
// is 48 B per pixel slab -> exactly 3 float4 loads, 16-B aligned (48 = 3*16,
// slab stride N*12 B is 16-B aligned when N%4==0).
// Per wave-request: 64 lanes * 16 B = 1 KB contiguous; 3 back-to-back = 3 KB
// per array per pixel (vs 768 B with dwordx3 one-window/thread).
// Nontemporal: data is read exactly once, skip L2 allocation.
__global__ __launch_bounds__(64) void spa_kernel_v4(
    const float* __restrict__ s1, const float* __restrict__ s2,
    float* __restrict__ out, int N, float scale) {
  const int g4 = blockIdx.x * 64 + (int)threadIdx.x;  // 4-window group id
  const int nG = N >> 2;

  // P[w][p]: pooled diff accumulator for window 4*g4+w, p=(i/4)*3+(j/4).
  float P[4][9];
#pragma unroll
  for (int w = 0; w < 4; ++w)
#pragma unroll
    for (int k = 0; k < 9; ++k) P[w][k] = 0.f;

  if (g4 < nG) {
    const size_t stride = (size_t)N * 3u;        // floats between pixel slabs
    const float* p1 = s1 + (size_t)g4 * 12u;     // 4 windows * 3 channels
    const float* p2 = s2 + (size_t)g4 * 12u;
#pragma unroll 1
    for (int i = 0; i < 12; ++i) {
      const int pr = (i >> 2) * 3;
#pragma unroll
      for (int j = 0; j < 12; ++j) {
        const f32x4* a = (const f32x4*)(p1 + (size_t)j * stride);
        const f32x4* b = (const f32x4*)(p2 + (size_t)j * stride);
        f32x4 a0 = __builtin_nontemporal_load(a);
        f32x4 a1 = __builtin_nontemporal_load(a + 1);
        f32x4 a2 = __builtin_nontemporal_load(a + 2);
        f32x4 b0 = __builtin_nontemporal_load(b);
        f32x4 b1 = __builtin_nontemporal_load(b + 1);
        f32x4 b2 = __builtin_nontemporal_load(b + 2);
        // 12 floats = 4 windows * {c0,c1,c2}
        float d0 = (a0.x + a0.y + a0.z) - (b0.x + b0.y + b0.z);
        float d1 = (a0.w + a1.x + a1.y) - (b0.w + b1.x + b1.y);
        float d2 = (a1.z + a1.w + a2.x) - (b1.z + b1.w + b2.x);
        float d3 = (a2.y + a2.z + a2.w) - (b2.y + b2.z + b2.w);
        const int pc = pr + (j >> 2);
        P[0][pc] += d0;
        P[1][pc] += d1;
        P[2][pc] += d2;
        P[3][pc] += d3;
      }
      p1 += (size_t)12 * stride;   // next pixel row
      p2 += (size_t)12 * stride;
    }
  }

  // Epilogue per window: /48, 4 directional grads (zero pad), squared sum.
  // Inactive threads have P=0 -> e=0.
  float e = 0.f;
#pragma unroll
  for (int w = 0; w < 4; ++w) {
    float Q[9];
#pragma unroll
    for (int k = 0; k < 9; ++k) Q[k] = P[w][k] * (1.0f / 48.0f);
#pragma unroll
    for (int i = 0; i < 3; ++i)
#pragma unroll
      for (int j = 0; j < 3; ++j) {
        float c = Q[i * 3 + j];
        float l = (j > 0) ? Q[i * 3 + j - 1] : 0.f;
        float r = (j < 2) ? Q[i * 3 + j + 1] : 0.f;
        float u = (i > 0) ? Q[(i - 1) * 3 + j] : 0.f;
        float d = (i < 2) ? Q[(i + 1) * 3 + j] : 0.f;
        float dl = c - l, dr = c - r, du = c - u, dd = c - d;
        e += dl * dl + dr * dr + du * du + dd * dd;
      }
  }

  // Single-wave block: wave reduce + one atomic.
#pragma unroll
  for (int off = 32; off > 0; off >>= 1) e += __shfl_down(e, off, 64);
  if ((threadIdx.x & 63) == 0) atomicAdd(out, e * scale);
}

// Scalar fallback for N % 4 != 0 (round-1 kernel, known-correct).
__global__ __launch_bounds__(512) void spa_kernel_s(
    const float* __restrict__ s1, const float* __restrict__ s2,
    float* __restrict__ out, int N, float scale) {
  const int win = blockIdx.x * 512 + threadIdx.x;
  float P[9];
#pragma unroll
  for (int k = 0; k < 9; ++k) P[k] = 0.f;

  if (win < N) {
    const size_t stride = (size_t)N * 3u;
    const float* p1 = s1 + (size_t)win * 3u;
    const float* p2 = s2 + (size_t)win * 3u;
#pragma unroll 1
    for (int i = 0; i < 12; ++i) {
      const int pr = (i >> 2) * 3;
#pragma unroll
      for (int j = 0; j < 12; ++j) {
        const float* a = p1 + (size_t)j * stride;
        const float* b = p2 + (size_t)j * stride;
        float d = (a[0] + a[1] + a[2]) - (b[0] + b[1] + b[2]);
        P[pr + (j >> 2)] += d;
      }
      p1 += (size_t)12 * stride;
      p2 += (size_t)12 * stride;
    }
  }

#pragma unroll
  for (int k = 0; k < 9; ++k) P[k] *= (1.0f / 48.0f);

  float e = 0.f;
#pragma unroll
  for (int i = 0; i < 3; ++i)
#pragma unroll
    for (int j = 0; j < 3; ++j) {
      float c = P[i * 3 + j];
      float l = (j > 0) ? P[i * 3 + j - 1] : 0.f;
      float r = (j < 2) ? P[i * 3 + j + 1] : 0.f;
      float u = (i > 0) ? P[(i - 1) * 3 + j] : 0.f;
      float d = (i < 2) ? P[(i + 1) * 3 + j] : 0.f;
      float dl = c - l, dr = c - r, du = c - u, dd = c - d;
      e += dl * dl + dr * dr + du * du + dd * dd;
    }

  const int lane = threadIdx.x & 63;
  const int wid = threadIdx.x >> 6;
#pragma unroll
  for (int off = 32; off > 0; off >>= 1) e += __shfl_down(e, off, 64);

  __shared__ float sPart[8];
  if (lane == 0) sPart[wid] = e;
  __syncthreads();
  if (threadIdx.x == 0) {
    float t = 0.f;
#pragma unroll
    for (int w = 0; w < 8; ++w) t += sPart[w];
    atomicAdd(out, t * scale);
  }
}

extern "C" void kernel_launch(void* const* d_in, const int* in_sizes, int n_in,
                              void* d_out, int out_size, void* d_ws, size_t ws_size,
                              hipStream_t stream) {
  const float* s1 = (const float*)d_in[0];
  const float* s2 = (const float*)d_in[1];
  float* out = (float*)d_out;
  int N = in_sizes[0] / (12 * 12 * 3);
  float scale = 1.0f / (9.0f * (float)N);
  hipMemsetAsync(d_out, 0, sizeof(float), stream);
  if ((N & 3) == 0) {
    int nG = N >> 2;
    int blocks = (nG + 63) / 64;
    spa_kernel_v4<<<blocks, 64, 0, stream>>>(s1, s2, out, N, scale);
  } else {
    int blocks = (N + 511) / 512;
    spa_kernel_s<<<blocks, 512, 0, stream>>>(s1, s2, out, N, scale);
  }
}

// Round 3
// 737.374 us; speedup vs baseline: 1.0211x; 1.0211x over previous
//
#include <hip/hip_runtime.h>

typedef float f32x4 __attribute__((ext_vector_type(4)));

// Vector path (requires N % 4 == 0).
// Layout of samples: [(pixel p)*N + n]*3 + c, p = i*12 + j.
// Work split: one 4-window group per lane, one POOL ROW (4 pixel rows) per
// wave. 3 waves/block of 64 lanes -> 192 threads; 150000 threads total =
// 2346 waves = 9.2 waves/CU (v4's failure was 3.05 waves/CU).
// Each 4-window group is 48 B per pixel slab -> exactly 3 aligned float4
// loads per array (1 KB contiguous per wave-instruction).
// Key structural trick: a pixel row belongs to exactly ONE pool row, so the
// per-thread accumulator is P[4 windows][3 pool cols] with ALL compile-time
// indices (no scratch), and rg only affects the base pointer. The 3 waves own
// disjoint pool rows -> no reduction, just concatenation through LDS.
__global__ __launch_bounds__(192) void spa_kernel_p3(
    const float* __restrict__ s1, const float* __restrict__ s2,
    float* __restrict__ out, int N, float scale) {
  const int lane = threadIdx.x & 63;
  const int rg   = threadIdx.x >> 6;        // pool row 0..2 (pixel rows 4rg..4rg+3)
  const int g4   = blockIdx.x * 64 + lane;  // 4-window group id
  const int nG   = N >> 2;

  // P[w][c]: sum over this pool row's 4x4 pixels (x3 channels) of (s1-s2),
  // for window 4*g4+w, pool col c.
  float P[4][3];
#pragma unroll
  for (int w = 0; w < 4; ++w)
#pragma unroll
    for (int c = 0; c < 3; ++c) P[w][c] = 0.f;

  if (g4 < nG) {
    const size_t stride = (size_t)N * 3u;       // floats between pixel slabs
    const size_t rowoff = (size_t)12 * stride;  // floats between pixel rows
    const float* p1 = s1 + (size_t)g4 * 12u + (size_t)(rg * 4) * rowoff;
    const float* p2 = s2 + (size_t)g4 * 12u + (size_t)(rg * 4) * rowoff;
#pragma unroll 1  // 4 pixel rows; keep rolled so ~72 loads/iter stage cleanly
    for (int ii = 0; ii < 4; ++ii) {
#pragma unroll
      for (int j = 0; j < 12; ++j) {
        const f32x4* a = (const f32x4*)(p1 + (size_t)j * stride);
        const f32x4* b = (const f32x4*)(p2 + (size_t)j * stride);
        f32x4 a0 = __builtin_nontemporal_load(a);
        f32x4 a1 = __builtin_nontemporal_load(a + 1);
        f32x4 a2 = __builtin_nontemporal_load(a + 2);
        f32x4 b0 = __builtin_nontemporal_load(b);
        f32x4 b1 = __builtin_nontemporal_load(b + 1);
        f32x4 b2 = __builtin_nontemporal_load(b + 2);
        // 12 floats = 4 windows * {c0,c1,c2}
        float d0 = (a0.x + a0.y + a0.z) - (b0.x + b0.y + b0.z);
        float d1 = (a0.w + a1.x + a1.y) - (b0.w + b1.x + b1.y);
        float d2 = (a1.z + a1.w + a2.x) - (b1.z + b1.w + b2.x);
        float d3 = (a2.y + a2.z + a2.w) - (b2.y + b2.z + b2.w);
        const int pc = j >> 2;  // compile-time: j-loop fully unrolled
        P[0][pc] += d0;
        P[1][pc] += d1;
        P[2][pc] += d2;
        P[3][pc] += d3;
      }
      p1 += rowoff;
      p2 += rowoff;
    }
  }

  // Waves 1,2 ship their pool row (12 floats) to wave 0. Stride 13 -> lane
  // step 13 banks, gcd(13,32)=1 -> 2 lanes/bank = conflict-free.
  __shared__ float sP[2][64][13];
  if (rg >= 1) {
#pragma unroll
    for (int w = 0; w < 4; ++w)
#pragma unroll
      for (int c = 0; c < 3; ++c) sP[rg - 1][lane][w * 3 + c] = P[w][c];
  }
  __syncthreads();

  if (rg == 0) {
    float e = 0.f;
#pragma unroll
    for (int w = 0; w < 4; ++w) {
      // Assemble full 3x3 pooled diff for window 4*g4+w; /48 = mean over
      // 3 channels * 16 pixels. Inactive lanes (g4>=nG) have all-zero P.
      float Q[9];
#pragma unroll
      for (int c = 0; c < 3; ++c) {
        Q[c]     = P[w][c] * (1.0f / 48.0f);
        Q[3 + c] = sP[0][lane][w * 3 + c] * (1.0f / 48.0f);
        Q[6 + c] = sP[1][lane][w * 3 + c] * (1.0f / 48.0f);
      }
      // 4 directional grads (zero padding), squared sum.
#pragma unroll
      for (int i = 0; i < 3; ++i)
#pragma unroll
        for (int j = 0; j < 3; ++j) {
          float cc = Q[i * 3 + j];
          float l = (j > 0) ? Q[i * 3 + j - 1] : 0.f;
          float r = (j < 2) ? Q[i * 3 + j + 1] : 0.f;
          float u = (i > 0) ? Q[(i - 1) * 3 + j] : 0.f;
          float d = (i < 2) ? Q[(i + 1) * 3 + j] : 0.f;
          float dl = cc - l, dr = cc - r, du = cc - u, dd = cc - d;
          e += dl * dl + dr * dr + du * du + dd * dd;
        }
    }
    // Wave reduce over 64 lanes (256 windows/block), one atomic per block.
#pragma unroll
    for (int off = 32; off > 0; off >>= 1) e += __shfl_down(e, off, 64);
    if (lane == 0) atomicAdd(out, e * scale);
  }
}

// Scalar fallback for N % 4 != 0 (round-1 kernel, known-correct, ~4.6 TB/s).
__global__ __launch_bounds__(512) void spa_kernel_s(
    const float* __restrict__ s1, const float* __restrict__ s2,
    float* __restrict__ out, int N, float scale) {
  const int win = blockIdx.x * 512 + threadIdx.x;
  float P[9];
#pragma unroll
  for (int k = 0; k < 9; ++k) P[k] = 0.f;

  if (win < N) {
    const size_t stride = (size_t)N * 3u;
    const float* p1 = s1 + (size_t)win * 3u;
    const float* p2 = s2 + (size_t)win * 3u;
#pragma unroll 1
    for (int i = 0; i < 12; ++i) {
      const int pr = (i >> 2) * 3;
#pragma unroll
      for (int j = 0; j < 12; ++j) {
        const float* a = p1 + (size_t)j * stride;
        const float* b = p2 + (size_t)j * stride;
        float d = (a[0] + a[1] + a[2]) - (b[0] + b[1] + b[2]);
        P[pr + (j >> 2)] += d;
      }
      p1 += (size_t)12 * stride;
      p2 += (size_t)12 * stride;
    }
  }

#pragma unroll
  for (int k = 0; k < 9; ++k) P[k] *= (1.0f / 48.0f);

  float e = 0.f;
#pragma unroll
  for (int i = 0; i < 3; ++i)
#pragma unroll
    for (int j = 0; j < 3; ++j) {
      float c = P[i * 3 + j];
      float l = (j > 0) ? P[i * 3 + j - 1] : 0.f;
      float r = (j < 2) ? P[i * 3 + j + 1] : 0.f;
      float u = (i > 0) ? P[(i - 1) * 3 + j] : 0.f;
      float d = (i < 2) ? P[(i + 1) * 3 + j] : 0.f;
      float dl = c - l, dr = c - r, du = c - u, dd = c - d;
      e += dl * dl + dr * dr + du * du + dd * dd;
    }

  const int lane = threadIdx.x & 63;
  const int wid = threadIdx.x >> 6;
#pragma unroll
  for (int off = 32; off > 0; off >>= 1) e += __shfl_down(e, off, 64);

  __shared__ float sPart[8];
  if (lane == 0) sPart[wid] = e;
  __syncthreads();
  if (threadIdx.x == 0) {
    float t = 0.f;
#pragma unroll
    for (int w = 0; w < 8; ++w) t += sPart[w];
    atomicAdd(out, t * scale);
  }
}

extern "C" void kernel_launch(void* const* d_in, const int* in_sizes, int n_in,
                              void* d_out, int out_size, void* d_ws, size_t ws_size,
                              hipStream_t stream) {
  const float* s1 = (const float*)d_in[0];
  const float* s2 = (const float*)d_in[1];
  float* out = (float*)d_out;
  int N = in_sizes[0] / (12 * 12 * 3);
  float scale = 1.0f / (9.0f * (float)N);
  hipMemsetAsync(d_out, 0, sizeof(float), stream);
  if ((N & 3) == 0) {
    int nG = N >> 2;
    int blocks = (nG + 63) / 64;
    spa_kernel_p3<<<blocks, 192, 0, stream>>>(s1, s2, out, N, scale);
  } else {
    int blocks = (N + 511) / 512;
    spa_kernel_s<<<blocks, 512, 0, stream>>>(s1, s2, out, N, scale);
  }
}

// Round 4
// 668.329 us; speedup vs baseline: 1.1266x; 1.1033x over previous
//
#include <hip/hip_runtime.h>

typedef float f32x4 __attribute__((ext_vector_type(4)));

// Vector path (requires N % 4 == 0).
// Layout of samples: [(pixel p)*N + n]*3 + c, p = i*12 + j.
// One 4-window group per lane; TWO pixel rows per wave (6 waves/block).
// Rows {2rg, 2rg+1} belong to pool row rg>>1, so the per-thread accumulator
// P[4 windows][3 pool cols] has all compile-time indices. 300000 threads =
// 4688 waves = 18.3 waves/CU launched (v4 failed at 3.05, p3 at 9.2).
// NO nontemporal: rounds 2-3 showed the NT read path caps ~3 TB/s on gfx950
// (weak wave-scaling + FETCH_SIZE undercount); round-1's plain loads hit
// 4.6 TB/s. Normal cached loads here.
// Each 4-window group is 48 B per pixel slab -> exactly 3 aligned float4
// loads per array (1 KB contiguous per wave-instruction).
__global__ __launch_bounds__(384) void spa_kernel_p6(
    const float* __restrict__ s1, const float* __restrict__ s2,
    float* __restrict__ out, int N, float scale) {
  const int lane = threadIdx.x & 63;
  const int rg   = threadIdx.x >> 6;        // 0..5: pixel rows {2rg, 2rg+1}
  const int g4   = blockIdx.x * 64 + lane;  // 4-window group id
  const int nG   = N >> 2;

  // P[w][c]: sum over this wave's 2 pixel rows (x12 cols x3 channels, folded
  // into pool col c) of (s1-s2), for window 4*g4+w.
  float P[4][3];
#pragma unroll
  for (int w = 0; w < 4; ++w)
#pragma unroll
    for (int c = 0; c < 3; ++c) P[w][c] = 0.f;

  if (g4 < nG) {
    const size_t stride = (size_t)N * 3u;       // floats between pixel slabs
    const size_t rowoff = (size_t)12 * stride;  // floats between pixel rows
    const float* p1 = s1 + (size_t)g4 * 12u + (size_t)(rg * 2) * rowoff;
    const float* p2 = s2 + (size_t)g4 * 12u + (size_t)(rg * 2) * rowoff;
#pragma unroll 1  // 2 pixel rows, keep rolled
    for (int ii = 0; ii < 2; ++ii) {
#pragma unroll
      for (int j = 0; j < 12; ++j) {
        const f32x4* a = (const f32x4*)(p1 + (size_t)j * stride);
        const f32x4* b = (const f32x4*)(p2 + (size_t)j * stride);
        f32x4 a0 = a[0], a1 = a[1], a2 = a[2];
        f32x4 b0 = b[0], b1 = b[1], b2 = b[2];
        // 12 floats = 4 windows * {c0,c1,c2}
        float d0 = (a0.x + a0.y + a0.z) - (b0.x + b0.y + b0.z);
        float d1 = (a0.w + a1.x + a1.y) - (b0.w + b1.x + b1.y);
        float d2 = (a1.z + a1.w + a2.x) - (b1.z + b1.w + b2.x);
        float d3 = (a2.y + a2.z + a2.w) - (b2.y + b2.z + b2.w);
        const int pc = j >> 2;  // compile-time: j fully unrolled
        P[0][pc] += d0;
        P[1][pc] += d1;
        P[2][pc] += d2;
        P[3][pc] += d3;
      }
      p1 += rowoff;
      p2 += rowoff;
    }
  }

  // Every wave ships its 12 partials; wave 0 combines. Row stride 13 floats:
  // gcd(13,32)=1 -> 2 lanes/bank per access = conflict-free.
  __shared__ float sP[6][64][13];
#pragma unroll
  for (int w = 0; w < 4; ++w)
#pragma unroll
    for (int c = 0; c < 3; ++c) sP[rg][lane][w * 3 + c] = P[w][c];
  __syncthreads();

  if (rg == 0) {
    float e = 0.f;
#pragma unroll
    for (int w = 0; w < 4; ++w) {
      // Pool row pr = waves 2pr and 2pr+1 summed; /48 = 3 channels * 16 px.
      float Q[9];
#pragma unroll
      for (int pr = 0; pr < 3; ++pr)
#pragma unroll
        for (int c = 0; c < 3; ++c)
          Q[pr * 3 + c] = (sP[2 * pr][lane][w * 3 + c] +
                           sP[2 * pr + 1][lane][w * 3 + c]) * (1.0f / 48.0f);
      // 4 directional grads (zero padding), squared sum. Inactive lanes: 0.
#pragma unroll
      for (int i = 0; i < 3; ++i)
#pragma unroll
        for (int j = 0; j < 3; ++j) {
          float cc = Q[i * 3 + j];
          float l = (j > 0) ? Q[i * 3 + j - 1] : 0.f;
          float r = (j < 2) ? Q[i * 3 + j + 1] : 0.f;
          float u = (i > 0) ? Q[(i - 1) * 3 + j] : 0.f;
          float d = (i < 2) ? Q[(i + 1) * 3 + j] : 0.f;
          float dl = cc - l, dr = cc - r, du = cc - u, dd = cc - d;
          e += dl * dl + dr * dr + du * du + dd * dd;
        }
    }
    // Wave reduce over 64 lanes (256 windows/block), one atomic per block.
#pragma unroll
    for (int off = 32; off > 0; off >>= 1) e += __shfl_down(e, off, 64);
    if (lane == 0) atomicAdd(out, e * scale);
  }
}

// Scalar fallback for N % 4 != 0 (round-1 kernel, known-correct, ~4.6 TB/s).
__global__ __launch_bounds__(512) void spa_kernel_s(
    const float* __restrict__ s1, const float* __restrict__ s2,
    float* __restrict__ out, int N, float scale) {
  const int win = blockIdx.x * 512 + threadIdx.x;
  float P[9];
#pragma unroll
  for (int k = 0; k < 9; ++k) P[k] = 0.f;

  if (win < N) {
    const size_t stride = (size_t)N * 3u;
    const float* p1 = s1 + (size_t)win * 3u;
    const float* p2 = s2 + (size_t)win * 3u;
#pragma unroll 1
    for (int i = 0; i < 12; ++i) {
      const int pr = (i >> 2) * 3;
#pragma unroll
      for (int j = 0; j < 12; ++j) {
        const float* a = p1 + (size_t)j * stride;
        const float* b = p2 + (size_t)j * stride;
        float d = (a[0] + a[1] + a[2]) - (b[0] + b[1] + b[2]);
        P[pr + (j >> 2)] += d;
      }
      p1 += (size_t)12 * stride;
      p2 += (size_t)12 * stride;
    }
  }

#pragma unroll
  for (int k = 0; k < 9; ++k) P[k] *= (1.0f / 48.0f);

  float e = 0.f;
#pragma unroll
  for (int i = 0; i < 3; ++i)
#pragma unroll
    for (int j = 0; j < 3; ++j) {
      float c = P[i * 3 + j];
      float l = (j > 0) ? P[i * 3 + j - 1] : 0.f;
      float r = (j < 2) ? P[i * 3 + j + 1] : 0.f;
      float u = (i > 0) ? P[(i - 1) * 3 + j] : 0.f;
      float d = (i < 2) ? P[(i + 1) * 3 + j] : 0.f;
      float dl = c - l, dr = c - r, du = c - u, dd = c - d;
      e += dl * dl + dr * dr + du * du + dd * dd;
    }

  const int lane = threadIdx.x & 63;
  const int wid = threadIdx.x >> 6;
#pragma unroll
  for (int off = 32; off > 0; off >>= 1) e += __shfl_down(e, off, 64);

  __shared__ float sPart[8];
  if (lane == 0) sPart[wid] = e;
  __syncthreads();
  if (threadIdx.x == 0) {
    float t = 0.f;
#pragma unroll
    for (int w = 0; w < 8; ++w) t += sPart[w];
    atomicAdd(out, t * scale);
  }
}

extern "C" void kernel_launch(void* const* d_in, const int* in_sizes, int n_in,
                              void* d_out, int out_size, void* d_ws, size_t ws_size,
                              hipStream_t stream) {
  const float* s1 = (const float*)d_in[0];
  const float* s2 = (const float*)d_in[1];
  float* out = (float*)d_out;
  int N = in_sizes[0] / (12 * 12 * 3);
  float scale = 1.0f / (9.0f * (float)N);
  hipMemsetAsync(d_out, 0, sizeof(float), stream);
  if ((N & 3) == 0) {
    int nG = N >> 2;
    int blocks = (nG + 63) / 64;
    spa_kernel_p6<<<blocks, 384, 0, stream>>>(s1, s2, out, N, scale);
  } else {
    int blocks = (N + 511) / 512;
    spa_kernel_s<<<blocks, 512, 0, stream>>>(s1, s2, out, N, scale);
  }
}

// Round 5
// 648.811 us; speedup vs baseline: 1.1605x; 1.0301x over previous
//
#include <hip/hip_runtime.h>

typedef float f32x4 __attribute__((ext_vector_type(4)));

// Transposed-work vector path (requires N % 4 == 0).
// Layout of samples: [(pixel p)*N + n]*3 + c, p = i*12 + j. One pixel "slab"
// = N*3 contiguous floats.
//
// Insight: the pooled diff P[n][pool] is LINEAR in the samples, so the load
// phase does not need window-aligned lanes. Each thread owns a fixed float4
// COLUMN of the slab dimension (lane-contiguous 16 B) and accumulates
// per-float partial sums over the 16 pixels of each pool of its pool row:
//   A[pc] += s1[pixel][col] - s2[pixel][col]   (f32x4, compile-time pc)
// -> every global load is a perfectly coalesced 1 KB wave instruction
//    (64 lanes x 16 B contiguous), the same shape as the 6.5 TB/s fills.
//    (Previous rounds' 48 B lane stride cost 3x line-requests/instr.)
// Cached (non-NT) loads keep the ~350 MB of L3 hits from the fill.
//
// Block = 576 threads = 3 pool-row teams x 192 float4 cols.
// 192 f4 = 768 floats = EXACTLY 256 windows -> channels never straddle blocks.
// Unscramble float->(window,channel) once at the end via LDS.
__global__ __launch_bounds__(576) void spa_kernel_t(
    const float* __restrict__ s1, const float* __restrict__ s2,
    float* __restrict__ out, int N, float scale) {
  const int tid  = threadIdx.x;
  const int col  = tid % 192;   // float4 column within block (wave-uniform rg)
  const int rg   = tid / 192;   // pool row 0..2 = pixel rows 4rg..4rg+3
  const int nF4  = (N >> 2) * 3;            // float4s per slab
  const int gcol = blockIdx.x * 192 + col;  // global float4 column

  // L[pr][pc][col]: per-float partial pool sums for this block's 768 floats.
  __shared__ f32x4 L[3][3][192];
  __shared__ float sPart[4];

  // A[pc]: f32x4 partial sums over the 16 pixels of pool (rg, pc).
  f32x4 A[3];
#pragma unroll
  for (int pc = 0; pc < 3; ++pc) A[pc] = {0.f, 0.f, 0.f, 0.f};

  if (gcol < nF4) {
    const size_t slab   = (size_t)N * 3u;   // floats per pixel slab
    const size_t rowoff = 12u * slab;       // floats per pixel row
    const float* p1 = s1 + (size_t)gcol * 4u + (size_t)(rg * 4) * rowoff;
    const float* p2 = s2 + (size_t)gcol * 4u + (size_t)(rg * 4) * rowoff;
#pragma unroll 1  // 4 pixel rows of this pool row
    for (int ii = 0; ii < 4; ++ii) {
#pragma unroll 6  // 12 loads (6 j x 2 arrays) in flight; bounds VGPR
      for (int j = 0; j < 12; ++j) {
        f32x4 a = *(const f32x4*)(p1 + (size_t)j * slab);
        f32x4 b = *(const f32x4*)(p2 + (size_t)j * slab);
        A[j >> 2] += a - b;  // j compile-time within unroll body
      }
      p1 += rowoff;
      p2 += rowoff;
    }
  }

  // Stage partial sums. Lane-contiguous b128 writes: conflict-free.
#pragma unroll
  for (int pc = 0; pc < 3; ++pc) L[rg][pc][col] = A[pc];
  __syncthreads();

  // Unscramble: thread w (<256) owns window blockIdx*256 + w, whose channels
  // are local floats 3w, 3w+1, 3w+2. Lane read stride 3 words -> 2 lanes/bank.
  if (tid < 256) {
    const float* Lf = (const float*)L;
    float e = 0.f;
    float Q[9];
#pragma unroll
    for (int pr = 0; pr < 3; ++pr)
#pragma unroll
      for (int pc = 0; pc < 3; ++pc) {
        const int base = (pr * 3 + pc) * 768 + 3 * tid;
        // mean over 3 channels * 16 pixels; inactive columns are zero.
        Q[pr * 3 + pc] = (Lf[base] + Lf[base + 1] + Lf[base + 2]) * (1.0f / 48.0f);
      }
    // 4 directional grads (zero padding), squared sum.
#pragma unroll
    for (int i = 0; i < 3; ++i)
#pragma unroll
      for (int j = 0; j < 3; ++j) {
        float cc = Q[i * 3 + j];
        float l = (j > 0) ? Q[i * 3 + j - 1] : 0.f;
        float r = (j < 2) ? Q[i * 3 + j + 1] : 0.f;
        float u = (i > 0) ? Q[(i - 1) * 3 + j] : 0.f;
        float d = (i < 2) ? Q[(i + 1) * 3 + j] : 0.f;
        float dl = cc - l, dr = cc - r, du = cc - u, dd = cc - d;
        e += dl * dl + dr * dr + du * du + dd * dd;
      }
    // Reduce 4 waves -> 1 atomic per block.
#pragma unroll
    for (int off = 32; off > 0; off >>= 1) e += __shfl_down(e, off, 64);
    if ((tid & 63) == 0) sPart[tid >> 6] = e;
  }
  __syncthreads();
  if (tid == 0)
    atomicAdd(out, (sPart[0] + sPart[1] + sPart[2] + sPart[3]) * scale);
}

// Scalar fallback for N % 4 != 0 (round-1 kernel, known-correct, ~4.6 TB/s).
__global__ __launch_bounds__(512) void spa_kernel_s(
    const float* __restrict__ s1, const float* __restrict__ s2,
    float* __restrict__ out, int N, float scale) {
  const int win = blockIdx.x * 512 + threadIdx.x;
  float P[9];
#pragma unroll
  for (int k = 0; k < 9; ++k) P[k] = 0.f;

  if (win < N) {
    const size_t stride = (size_t)N * 3u;
    const float* p1 = s1 + (size_t)win * 3u;
    const float* p2 = s2 + (size_t)win * 3u;
#pragma unroll 1
    for (int i = 0; i < 12; ++i) {
      const int pr = (i >> 2) * 3;
#pragma unroll
      for (int j = 0; j < 12; ++j) {
        const float* a = p1 + (size_t)j * stride;
        const float* b = p2 + (size_t)j * stride;
        float d = (a[0] + a[1] + a[2]) - (b[0] + b[1] + b[2]);
        P[pr + (j >> 2)] += d;
      }
      p1 += (size_t)12 * stride;
      p2 += (size_t)12 * stride;
    }
  }

#pragma unroll
  for (int k = 0; k < 9; ++k) P[k] *= (1.0f / 48.0f);

  float e = 0.f;
#pragma unroll
  for (int i = 0; i < 3; ++i)
#pragma unroll
    for (int j = 0; j < 3; ++j) {
      float c = P[i * 3 + j];
      float l = (j > 0) ? P[i * 3 + j - 1] : 0.f;
      float r = (j < 2) ? P[i * 3 + j + 1] : 0.f;
      float u = (i > 0) ? P[(i - 1) * 3 + j] : 0.f;
      float d = (i < 2) ? P[(i + 1) * 3 + j] : 0.f;
      float dl = c - l, dr = c - r, du = c - u, dd = c - d;
      e += dl * dl + dr * dr + du * du + dd * dd;
    }

  const int lane = threadIdx.x & 63;
  const int wid = threadIdx.x >> 6;
#pragma unroll
  for (int off = 32; off > 0; off >>= 1) e += __shfl_down(e, off, 64);

  __shared__ float sPartS[8];
  if (lane == 0) sPartS[wid] = e;
  __syncthreads();
  if (threadIdx.x == 0) {
    float t = 0.f;
#pragma unroll
    for (int w = 0; w < 8; ++w) t += sPartS[w];
    atomicAdd(out, t * scale);
  }
}

extern "C" void kernel_launch(void* const* d_in, const int* in_sizes, int n_in,
                              void* d_out, int out_size, void* d_ws, size_t ws_size,
                              hipStream_t stream) {
  const float* s1 = (const float*)d_in[0];
  const float* s2 = (const float*)d_in[1];
  float* out = (float*)d_out;
  int N = in_sizes[0] / (12 * 12 * 3);
  float scale = 1.0f / (9.0f * (float)N);
  hipMemsetAsync(d_out, 0, sizeof(float), stream);
  if ((N & 3) == 0) {
    int nF4 = (N >> 2) * 3;
    int blocks = (nF4 + 191) / 192;
    spa_kernel_t<<<blocks, 576, 0, stream>>>(s1, s2, out, N, scale);
  } else {
    int blocks = (N + 511) / 512;
    spa_kernel_s<<<blocks, 512, 0, stream>>>(s1, s2, out, N, scale);
  }
}